// Round 22
// baseline (686.737 us; speedup 1.0000x reference)
//
#include <hip/hip_runtime.h>
#include <hip/hip_bf16.h>
#include <cstdint>

typedef unsigned short u16;
typedef __bf16 bf16x8 __attribute__((ext_vector_type(8)));
typedef float f32x4 __attribute__((ext_vector_type(4)));

#define DEV __device__ __forceinline__

static constexpr int BATCH = 1024, SEQ = 49, DIM = 448;
static constexpr int NH = 8, DV = 128;
static constexpr int QKV_N = 1536, MLP_H = 1792;
static constexpr float SCALE = 0.17677669529663687f;  // 32^-0.5

DEV u16 f2bf(float f) {
    uint32_t u = __builtin_bit_cast(uint32_t, f);
    u += 0x7fffu + ((u >> 16) & 1u);
    return (u16)(u >> 16);
}

DEV float bf2f(u16 h) {
    uint32_t u = (uint32_t)h << 16;
    return __builtin_bit_cast(float, u);
}

DEV void gload16(const void* g, void* l) {
    __builtin_amdgcn_global_load_lds(
        (__attribute__((address_space(1))) void*)const_cast<void*>(g),
        (__attribute__((address_space(3))) void*)l, 16, 0, 0);
}

#define MFMA(a, b, c) __builtin_amdgcn_mfma_f32_16x16x32_bf16((a), (b), (c), 0, 0, 0)

// ---------------- weight transpose+cast:  src[K][N] f32 -> dst[Npad][K] bf16
__global__ __launch_bounds__(256) void transpose_cast(const float* __restrict__ src,
                                                      u16* __restrict__ dst,
                                                      int K, int N, int Npad) {
    __shared__ float t[32][33];
    int nbk = K >> 5;
    int bk = blockIdx.x % nbk;
    int bn = blockIdx.x / nbk;
    int lx = threadIdx.x & 31, ly = threadIdx.x >> 5;  // 32 x 8
    int n0 = bn * 32, k0 = bk * 32;
    #pragma unroll
    for (int i = 0; i < 32; i += 8) {
        int k = k0 + ly + i, n = n0 + lx;
        t[ly + i][lx] = (n < N) ? src[(size_t)k * N + n] : 0.f;
    }
    __syncthreads();
    #pragma unroll
    for (int i = 0; i < 32; i += 8) {
        int n = n0 + ly + i, k = k0 + lx;
        dst[(size_t)n * K + k] = f2bf(t[lx][ly + i]);
    }
}

// ---------------- expand attention bias: tab[h][49][49]
__global__ void build_bias(const float* __restrict__ ab, const int* __restrict__ idxs,
                           float* __restrict__ tab, int n_off) {
    int i = blockIdx.x * 256 + threadIdx.x;
    if (i >= NH * 49 * 49) return;
    int h = i / 2401, rem = i % 2401;
    tab[i] = ab[h * n_off + idxs[rem]];
}

// ---------------- LayerNorm f32 -> bf16, rows of 448, one wave per row
// Also emits a bf16 copy of the raw input (xcopy) for the residual path.
__global__ __launch_bounds__(256) void ln_kernel(const float* __restrict__ x,
                                                 const float* __restrict__ g,
                                                 const float* __restrict__ bb,
                                                 u16* __restrict__ out,
                                                 u16* __restrict__ xcopy) {
    int row = blockIdx.x * 4 + (threadIdx.x >> 6);
    int l = threadIdx.x & 63;
    const float* xr = x + (size_t)row * DIM;
    float v[7];
    float s = 0.f;
    #pragma unroll
    for (int j = 0; j < 7; j++) { v[j] = xr[l + j * 64]; s += v[j]; }
    #pragma unroll
    for (int m = 32; m; m >>= 1) s += __shfl_xor(s, m, 64);
    float mu = s * (1.f / 448.f);
    float var = 0.f;
    #pragma unroll
    for (int j = 0; j < 7; j++) { float d = v[j] - mu; var += d * d; }
    #pragma unroll
    for (int m = 32; m; m >>= 1) var += __shfl_xor(var, m, 64);
    float rs = rsqrtf(var * (1.f / 448.f) + 1e-5f);
    u16* orow = out + (size_t)row * DIM;
    u16* crow = xcopy + (size_t)row * DIM;
    #pragma unroll
    for (int j = 0; j < 7; j++) {
        int c = l + j * 64;
        orow[c] = f2bf((v[j] - mu) * rs * g[c] + bb[c]);
        crow[c] = f2bf(v[j]);
    }
}

// ---------------- LayerNorm bf16 -> bf16 (same structure, bf16 input)
__global__ __launch_bounds__(256) void ln16_kernel(const u16* __restrict__ x,
                                                   const float* __restrict__ g,
                                                   const float* __restrict__ bb,
                                                   u16* __restrict__ out) {
    int row = blockIdx.x * 4 + (threadIdx.x >> 6);
    int l = threadIdx.x & 63;
    const u16* xr = x + (size_t)row * DIM;
    float v[7];
    float s = 0.f;
    #pragma unroll
    for (int j = 0; j < 7; j++) { v[j] = bf2f(xr[l + j * 64]); s += v[j]; }
    #pragma unroll
    for (int m = 32; m; m >>= 1) s += __shfl_xor(s, m, 64);
    float mu = s * (1.f / 448.f);
    float var = 0.f;
    #pragma unroll
    for (int j = 0; j < 7; j++) { float d = v[j] - mu; var += d * d; }
    #pragma unroll
    for (int m = 32; m; m >>= 1) var += __shfl_xor(var, m, 64);
    float rs = rsqrtf(var * (1.f / 448.f) + 1e-5f);
    u16* orow = out + (size_t)row * DIM;
    #pragma unroll
    for (int j = 0; j < 7; j++) {
        int c = l + j * 64;
        orow[c] = f2bf((v[j] - mu) * rs * g[c] + bb[c]);
    }
}

// ---------------- GEMM: A[Mreal][K] bf16 row-major x BT[N][K] bf16 -> epilogue
// r16 structure (BEST): 128x128 tile, 8 waves x 64Mx32N, BK=32 depth-2 dbuf at
// 32 KB footprint (4 blocks/CU, 68% occ), counted vmcnt(2) prefetch.
// Swizzle: chunk ^ ((row>>1)&3). XCD-bijective grid swizzle.
// EPI 0: out_bf16 = acc + bias                             (ld = Nreal)
// EPI 1: out_bf16 = gelu(acc + bias)                       (ld = Nreal)
// EPI 2: out_bf16 = f2bf(bf2f(xres16) + ls*(acc+bias))     (ld = DIM)
// EPI 3: out_f32  = bf2f(xres16) + ls*(acc+bias)           (ld = DIM)
template <int EPI>
__global__ __launch_bounds__(512, 6) void gemm128(const u16* __restrict__ A,
                                                  const u16* __restrict__ BT,
                                                  int Mreal, int N, int K, int Nreal,
                                                  const float* __restrict__ bias,
                                                  const float* __restrict__ ls,
                                                  const u16* __restrict__ xres16,
                                                  u16* __restrict__ outB,
                                                  float* __restrict__ outF) {
    __shared__ __align__(16) u16 sa[2][128 * 32];  // 2 x 8 KB
    __shared__ __align__(16) u16 sb[2][128 * 32];  // 2 x 8 KB
    const int tid = threadIdx.x;
    const int tilesN = N >> 7;

    // XCD-aware bijective swizzle (grids here are divisible by 8)
    int bid = blockIdx.x;
    int nwg = gridDim.x;
    if ((nwg & 7) == 0) {
        int cpx = nwg >> 3;
        bid = (bid & 7) * cpx + (bid >> 3);
    }
    const int tm = bid / tilesN, tn = bid % tilesN;

    const int w = tid >> 6, l = tid & 63;
    const int wm = (w >> 2) * 64, wn = (w & 3) * 32;
    const int l15 = l & 15, l4 = l >> 4;

    // staging addresses (loop-invariant): thread loads 1 A chunk + 1 B chunk
    const int srow = tid >> 2, scol = tid & 3;
    const int scs = scol ^ ((srow >> 1) & 3);  // pre-swizzled global chunk
    int gm = tm * 128 + srow;
    gm = gm < Mreal ? gm : Mreal - 1;  // clamp (stores guarded)
    const u16* gA0 = A + (size_t)gm * K + scs * 8;
    const u16* gB0 = BT + (size_t)(tn * 128 + srow) * K + scs * 8;
    const int loff = tid * 8;  // linear in lane (gload_lds requirement)

    auto STAGE = [&](int buf, int kt) {
        const int k0 = kt << 5;
        gload16(gA0 + k0, &sa[buf][loff]);
        gload16(gB0 + k0, &sb[buf][loff]);
    };

    f32x4 acc[4][2];
    #pragma unroll
    for (int i = 0; i < 4; i++)
        #pragma unroll
        for (int j = 0; j < 2; j++) acc[i][j] = (f32x4){0.f, 0.f, 0.f, 0.f};

    const int nk = K >> 5;  // >= 14 for all shapes here
    STAGE(0, 0);
    STAGE(1, 1);

    #pragma unroll 1
    for (int kt = 0; kt < nk; ++kt) {
        const int cur = kt & 1;
        if (kt + 1 < nk) {
            asm volatile("s_waitcnt vmcnt(2)" ::: "memory");  // tile kt landed
        } else {
            asm volatile("s_waitcnt vmcnt(0)" ::: "memory");  // last tile
        }
        __builtin_amdgcn_s_barrier();
        __builtin_amdgcn_sched_barrier(0);
        {
            bf16x8 af[4], bfr[2];
            #pragma unroll
            for (int i = 0; i < 4; i++) {
                int row = wm + i * 16 + l15;
                int c = l4 ^ ((row >> 1) & 3);
                af[i] = *(const bf16x8*)&sa[cur][row * 32 + c * 8];
            }
            #pragma unroll
            for (int j = 0; j < 2; j++) {
                int row = wn + j * 16 + l15;
                int c = l4 ^ ((row >> 1) & 3);
                bfr[j] = *(const bf16x8*)&sb[cur][row * 32 + c * 8];
            }
            #pragma unroll
            for (int i = 0; i < 4; i++)
                #pragma unroll
                for (int j = 0; j < 2; j++)
                    acc[i][j] = MFMA(af[i], bfr[j], acc[i][j]);
        }
        __builtin_amdgcn_s_barrier();  // all waves done reading buf cur
        __builtin_amdgcn_sched_barrier(0);
        if (kt + 2 < nk) STAGE(cur, kt + 2);  // refill freed buf; stays in flight
    }

    #pragma unroll
    for (int i = 0; i < 4; i++) {
        int row0 = tm * 128 + wm + i * 16 + l4 * 4;
        #pragma unroll
        for (int j = 0; j < 2; j++) {
            int col = tn * 128 + wn + j * 16 + l15;
            if (col >= Nreal) continue;
            float bv = bias[col];
            #pragma unroll
            for (int r = 0; r < 4; r++) {
                int m = row0 + r;
                if (m >= Mreal) continue;
                float v = acc[i][j][r] + bv;
                if (EPI == 0) {
                    outB[(size_t)m * Nreal + col] = f2bf(v);
                } else if (EPI == 1) {
                    float gl = 0.5f * v * (1.f + erff(v * 0.70710678118654752f));
                    outB[(size_t)m * Nreal + col] = f2bf(gl);
                } else if (EPI == 2) {
                    outB[(size_t)m * DIM + col] =
                        f2bf(bf2f(xres16[(size_t)m * DIM + col]) + ls[col] * v);
                } else {
                    outF[(size_t)m * DIM + col] =
                        bf2f(xres16[(size_t)m * DIM + col]) + ls[col] * v;
                }
            }
        }
    }
}

// ---------------- attention: one block per (b_local,h), 4 waves
__global__ __launch_bounds__(256) void attn_kernel(const u16* __restrict__ qkv,
                                                   const float* __restrict__ btab,
                                                   u16* __restrict__ ctx) {
    __shared__ __align__(16) u16 sq[64 * 40];
    __shared__ __align__(16) u16 sk[64 * 40];
    __shared__ __align__(16) u16 sv[128 * 72];  // v transposed [d][s]
    __shared__ __align__(16) u16 sp[64 * 72];   // probs bf16
    const int tid = threadIdx.x;
    const int bh = blockIdx.x;
    const int b = bh >> 3, h = bh & 7;
    const int w = tid >> 6, l = tid & 63, l15 = l & 15, l4 = l >> 4;
    const f32x4 Z4 = {0.f, 0.f, 0.f, 0.f};
    const size_t rowbase = (size_t)(b * SEQ) * QKV_N + h * 192;

    for (int c = tid; c < SEQ * 4; c += 256) {
        int s = c >> 2, ch = c & 3;
        *(uint4*)&sq[s * 40 + ch * 8] = *(const uint4*)(qkv + rowbase + (size_t)s * QKV_N + ch * 8);
        *(uint4*)&sk[s * 40 + ch * 8] = *(const uint4*)(qkv + rowbase + (size_t)s * QKV_N + 32 + ch * 8);
    }
    for (int c = tid; c < 15 * 5; c += 256) {
        int s = SEQ + c / 5, ch = c % 5;
        *(uint4*)&sq[s * 40 + ch * 8] = (uint4){0, 0, 0, 0};
        *(uint4*)&sk[s * 40 + ch * 8] = (uint4){0, 0, 0, 0};
    }
    for (int c = tid; c < SEQ * 16; c += 256) {
        int s = c >> 4, ch = c & 15;
        uint4 vv = *(const uint4*)(qkv + rowbase + (size_t)s * QKV_N + 64 + ch * 8);
        const u16* pv = (const u16*)&vv;
        #pragma unroll
        for (int j = 0; j < 8; j++) sv[(ch * 8 + j) * 72 + s] = pv[j];
    }
    for (int c = tid; c < 128 * 15; c += 256) {
        int d = c / 15, s = SEQ + c % 15;
        sv[d * 72 + s] = 0;
    }
    __syncthreads();

    bf16x8 aq = *(const bf16x8*)&sq[(w * 16 + l15) * 40 + l4 * 8];
    f32x4 sc[4];
    #pragma unroll
    for (int j = 0; j < 4; j++) {
        bf16x8 bk = *(const bf16x8*)&sk[(j * 16 + l15) * 40 + l4 * 8];
        sc[j] = MFMA(aq, bk, Z4);
    }
    #pragma unroll
    for (int r = 0; r < 4; r++) {
        int row = w * 16 + l4 * 4 + r;
        float pv[4];
        #pragma unroll
        for (int j = 0; j < 4; j++) {
            int col = j * 16 + l15;
            float sval = -1e30f;
            if (row < SEQ && col < SEQ)
                sval = sc[j][r] * SCALE + btab[(h * SEQ + row) * SEQ + col];
            pv[j] = sval;
        }
        float m = fmaxf(fmaxf(pv[0], pv[1]), fmaxf(pv[2], pv[3]));
        #pragma unroll
        for (int mask = 1; mask < 16; mask <<= 1) m = fmaxf(m, __shfl_xor(m, mask, 16));
        float s = 0.f;
        #pragma unroll
        for (int j = 0; j < 4; j++) { pv[j] = expf(pv[j] - m); s += pv[j]; }
        #pragma unroll
        for (int mask = 1; mask < 16; mask <<= 1) s += __shfl_xor(s, mask, 16);
        float inv = 1.f / s;
        #pragma unroll
        for (int j = 0; j < 4; j++) sp[row * 72 + j * 16 + l15] = f2bf(pv[j] * inv);
    }
    __syncthreads();

    bf16x8 ap0 = *(const bf16x8*)&sp[(w * 16 + l15) * 72 + l4 * 8];
    bf16x8 ap1 = *(const bf16x8*)&sp[(w * 16 + l15) * 72 + 32 + l4 * 8];
    #pragma unroll
    for (int j = 0; j < 8; j++) {
        bf16x8 b0 = *(const bf16x8*)&sv[(j * 16 + l15) * 72 + l4 * 8];
        bf16x8 b1 = *(const bf16x8*)&sv[(j * 16 + l15) * 72 + 32 + l4 * 8];
        f32x4 a = MFMA(ap0, b0, Z4);
        a = MFMA(ap1, b1, a);
        #pragma unroll
        for (int r = 0; r < 4; r++) {
            int row = w * 16 + l4 * 4 + r;
            if (row < SEQ)
                ctx[((size_t)(b * SEQ) + row) * 1024 + h * DV + j * 16 + l15] = f2bf(a[r]);
        }
    }
}

extern "C" void kernel_launch(void* const* d_in, const int* in_sizes, int n_in,
                              void* d_out, int out_size, void* d_ws, size_t ws_size,
                              hipStream_t stream) {
    const float* x = (const float*)d_in[0];
    const float* qkv_w = (const float*)d_in[1];
    const float* qkv_b = (const float*)d_in[2];
    const float* proj_w = (const float*)d_in[3];
    const float* proj_b = (const float*)d_in[4];
    const float* ln1_g = (const float*)d_in[5];
    const float* ln1_b = (const float*)d_in[6];
    const float* ln2_g = (const float*)d_in[7];
    const float* ln2_b = (const float*)d_in[8];
    const float* mlp_w1 = (const float*)d_in[9];
    const float* mlp_b1 = (const float*)d_in[10];
    const float* mlp_w2 = (const float*)d_in[11];
    const float* mlp_b2 = (const float*)d_in[12];
    const float* attn_biases = (const float*)d_in[13];
    const float* ls1 = (const float*)d_in[14];
    const float* ls2 = (const float*)d_in[15];
    const int* bias_idxs = (const int*)d_in[16];
    int n_off = in_sizes[13] / NH;
    float* out = (float*)d_out;

    auto al = [](size_t b) { return (b + 255) & ~(size_t)255; };
    const size_t wbytes = al((size_t)QKV_N * DIM * 2) + al((size_t)512 * 1024 * 2) +
                          al((size_t)MLP_H * DIM * 2) + al((size_t)512 * MLP_H * 2) +
                          al((size_t)NH * 2401 * 4);

    // pick largest chunk (fewest chunks) that fits ws_size (r20 formula:
    // the bf16 x-copy lives in d_out's chunk region, costing no workspace)
    int nc = 32;
    {
        const int cands[6] = {1, 2, 4, 8, 16, 32};
        for (int ci = 0; ci < 6; ci++) {
            size_t R = (size_t)(BATCH / cands[ci]) * SEQ;
            size_t need = wbytes + al(R * DIM * 2) + al(R * MLP_H * 2) + al(R * 1024 * 2);
            if (need <= ws_size) { nc = cands[ci]; break; }
        }
    }
    const int CH = BATCH / nc;      // batches per chunk
    const int R = CH * SEQ;         // rows per chunk
    const int MT = (R + 127) >> 7;  // M tiles per chunk

    char* ws = (char*)d_ws;
    size_t off = 0;
    auto alloc = [&](size_t bytes) {
        void* p = ws + off;
        off += al(bytes);
        return p;
    };
    u16* wt_qkv = (u16*)alloc((size_t)QKV_N * DIM * 2);
    u16* wt_proj = (u16*)alloc((size_t)512 * 1024 * 2);
    u16* wt_m1 = (u16*)alloc((size_t)MLP_H * DIM * 2);
    u16* wt_m2 = (u16*)alloc((size_t)512 * MLP_H * 2);
    float* btab = (float*)alloc((size_t)NH * 2401 * 4);
    u16* hbuf = (u16*)alloc((size_t)R * DIM * 2);   // h(LN1) -> xmid16 (proj out)
    u16* big = (u16*)alloc((size_t)R * MLP_H * 2);  // qkv -> m1
    u16* ctx = (u16*)alloc((size_t)R * 1024 * 2);   // attn ctx -> h2(LN2 out)

    transpose_cast<<<(DIM / 32) * (QKV_N / 32), 256, 0, stream>>>(qkv_w, wt_qkv, DIM, QKV_N, QKV_N);
    transpose_cast<<<(1024 / 32) * (512 / 32), 256, 0, stream>>>(proj_w, wt_proj, 1024, DIM, 512);
    transpose_cast<<<(DIM / 32) * (MLP_H / 32), 256, 0, stream>>>(mlp_w1, wt_m1, DIM, MLP_H, MLP_H);
    transpose_cast<<<(MLP_H / 32) * (512 / 32), 256, 0, stream>>>(mlp_w2, wt_m2, MLP_H, DIM, 512);
    build_bias<<<(NH * 2401 + 255) / 256, 256, 0, stream>>>(attn_biases, bias_idxs, btab, n_off);

    for (int c = 0; c < nc; ++c) {
        const float* xc = x + (size_t)c * R * DIM;
        float* oc = out + (size_t)c * R * DIM;
        u16* xbuf = (u16*)oc;  // bf16 x-copy lives in this chunk's out region
                               // (dead until MLP2's final f32 write)

        // LN1: x (f32) -> h (bf16, hbuf) + x16 copy (xbuf = oc)
        ln_kernel<<<R / 4, 256, 0, stream>>>(xc, ln1_g, ln1_b, hbuf, xbuf);
        // QKV: h @ Wqkv -> big
        gemm128<0><<<MT * (QKV_N / 128), 512, 0, stream>>>(
            hbuf, wt_qkv, R, QKV_N, DIM, QKV_N, qkv_b, nullptr, nullptr, big, nullptr);
        // attention: big -> ctx
        attn_kernel<<<CH * NH, 256, 0, stream>>>(big, btab, ctx);
        // proj + residual1 (bf16 x from oc) -> xmid16 in hbuf
        gemm128<2><<<MT * 4, 512, 0, stream>>>(
            ctx, wt_proj, R, 512, 1024, DIM, proj_b, ls1, xbuf, hbuf, nullptr);
        // LN2: xmid16 (hbuf) -> h2 (ctx; dead after proj)
        ln16_kernel<<<R / 4, 256, 0, stream>>>(hbuf, ln2_g, ln2_b, ctx);
        // MLP1 + gelu: h2 (ctx) -> big (qkv dead)
        gemm128<1><<<MT * (MLP_H / 128), 512, 0, stream>>>(
            ctx, wt_m1, R, MLP_H, DIM, MLP_H, mlp_b1, nullptr, nullptr, big, nullptr);
        // MLP2 + residual2: big, xmid16 (hbuf) -> out (f32, overwrites x16)
        gemm128<3><<<MT * 4, 512, 0, stream>>>(
            big, wt_m2, R, 512, MLP_H, DIM, mlp_b2, ls2, hbuf, nullptr, oc);
    }
}

// Round 23
// 675.609 us; speedup vs baseline: 1.0165x; 1.0165x over previous
//
#include <hip/hip_runtime.h>
#include <hip/hip_bf16.h>
#include <cstdint>

typedef unsigned short u16;
typedef __bf16 bf16x8 __attribute__((ext_vector_type(8)));
typedef float f32x4 __attribute__((ext_vector_type(4)));

#define DEV __device__ __forceinline__

static constexpr int BATCH = 1024, SEQ = 49, DIM = 448;
static constexpr int NH = 8, DV = 128;
static constexpr int QKV_N = 1536, MLP_H = 1792;
static constexpr float SCALE = 0.17677669529663687f;  // 32^-0.5

DEV u16 f2bf(float f) {
    uint32_t u = __builtin_bit_cast(uint32_t, f);
    u += 0x7fffu + ((u >> 16) & 1u);
    return (u16)(u >> 16);
}

DEV float bf2f(u16 h) {
    uint32_t u = (uint32_t)h << 16;
    return __builtin_bit_cast(float, u);
}

DEV void gload16(const void* g, void* l) {
    __builtin_amdgcn_global_load_lds(
        (__attribute__((address_space(1))) void*)const_cast<void*>(g),
        (__attribute__((address_space(3))) void*)l, 16, 0, 0);
}

#define MFMA(a, b, c) __builtin_amdgcn_mfma_f32_16x16x32_bf16((a), (b), (c), 0, 0, 0)

// ---------------- weight transpose+cast:  src[K][N] f32 -> dst[Npad][K] bf16
__global__ __launch_bounds__(256) void transpose_cast(const float* __restrict__ src,
                                                      u16* __restrict__ dst,
                                                      int K, int N, int Npad) {
    __shared__ float t[32][33];
    int nbk = K >> 5;
    int bk = blockIdx.x % nbk;
    int bn = blockIdx.x / nbk;
    int lx = threadIdx.x & 31, ly = threadIdx.x >> 5;  // 32 x 8
    int n0 = bn * 32, k0 = bk * 32;
    #pragma unroll
    for (int i = 0; i < 32; i += 8) {
        int k = k0 + ly + i, n = n0 + lx;
        t[ly + i][lx] = (n < N) ? src[(size_t)k * N + n] : 0.f;
    }
    __syncthreads();
    #pragma unroll
    for (int i = 0; i < 32; i += 8) {
        int n = n0 + ly + i, k = k0 + lx;
        dst[(size_t)n * K + k] = f2bf(t[lx][ly + i]);
    }
}

// ---------------- expand attention bias: tab[h][49][49]
__global__ void build_bias(const float* __restrict__ ab, const int* __restrict__ idxs,
                           float* __restrict__ tab, int n_off) {
    int i = blockIdx.x * 256 + threadIdx.x;
    if (i >= NH * 49 * 49) return;
    int h = i / 2401, rem = i % 2401;
    tab[i] = ab[h * n_off + idxs[rem]];
}

// ---------------- LayerNorm f32 -> bf16, rows of 448, one wave per row
__global__ __launch_bounds__(256) void ln_kernel(const float* __restrict__ x,
                                                 const float* __restrict__ g,
                                                 const float* __restrict__ bb,
                                                 u16* __restrict__ out) {
    int row = blockIdx.x * 4 + (threadIdx.x >> 6);
    int l = threadIdx.x & 63;
    const float* xr = x + (size_t)row * DIM;
    float v[7];
    float s = 0.f;
    #pragma unroll
    for (int j = 0; j < 7; j++) { v[j] = xr[l + j * 64]; s += v[j]; }
    #pragma unroll
    for (int m = 32; m; m >>= 1) s += __shfl_xor(s, m, 64);
    float mu = s * (1.f / 448.f);
    float var = 0.f;
    #pragma unroll
    for (int j = 0; j < 7; j++) { float d = v[j] - mu; var += d * d; }
    #pragma unroll
    for (int m = 32; m; m >>= 1) var += __shfl_xor(var, m, 64);
    float rs = rsqrtf(var * (1.f / 448.f) + 1e-5f);
    u16* orow = out + (size_t)row * DIM;
    #pragma unroll
    for (int j = 0; j < 7; j++) {
        int c = l + j * 64;
        orow[c] = f2bf((v[j] - mu) * rs * g[c] + bb[c]);
    }
}

// ---------------- LayerNorm bf16 -> bf16 (same structure, bf16 input)
__global__ __launch_bounds__(256) void ln16_kernel(const u16* __restrict__ x,
                                                   const float* __restrict__ g,
                                                   const float* __restrict__ bb,
                                                   u16* __restrict__ out) {
    int row = blockIdx.x * 4 + (threadIdx.x >> 6);
    int l = threadIdx.x & 63;
    const u16* xr = x + (size_t)row * DIM;
    float v[7];
    float s = 0.f;
    #pragma unroll
    for (int j = 0; j < 7; j++) { v[j] = bf2f(xr[l + j * 64]); s += v[j]; }
    #pragma unroll
    for (int m = 32; m; m >>= 1) s += __shfl_xor(s, m, 64);
    float mu = s * (1.f / 448.f);
    float var = 0.f;
    #pragma unroll
    for (int j = 0; j < 7; j++) { float d = v[j] - mu; var += d * d; }
    #pragma unroll
    for (int m = 32; m; m >>= 1) var += __shfl_xor(var, m, 64);
    float rs = rsqrtf(var * (1.f / 448.f) + 1e-5f);
    u16* orow = out + (size_t)row * DIM;
    #pragma unroll
    for (int j = 0; j < 7; j++) {
        int c = l + j * 64;
        orow[c] = f2bf((v[j] - mu) * rs * g[c] + bb[c]);
    }
}

// ---------------- GEMM: A[Mreal][K] bf16 row-major x BT[N][K] bf16 -> epilogue
// r16 structure (BEST): 128x128 tile, 8 waves x 64Mx32N, BK=32 depth-2 dbuf at
// 32 KB footprint (4 blocks/CU, 68% occ), counted vmcnt(2) prefetch.
// Swizzle: chunk ^ ((row>>1)&3). XCD-bijective grid swizzle.
// EPI 0: out_bf16 = acc + bias                     (ld = Nreal)
// EPI 1: out_bf16 = gelu(acc + bias)               (ld = Nreal)
// EPI 2: out_bf16 = f2bf(xresF + ls*(acc+bias))    (ld = DIM; xmid16)
// EPI 3: out_f32  = bf2f(xres16) + ls*(acc+bias)   (ld = DIM)
template <int EPI>
__global__ __launch_bounds__(512, 6) void gemm128(const u16* __restrict__ A,
                                                  const u16* __restrict__ BT,
                                                  int Mreal, int N, int K, int Nreal,
                                                  const float* __restrict__ bias,
                                                  const float* __restrict__ ls,
                                                  const float* __restrict__ xresF,
                                                  const u16* __restrict__ xres16,
                                                  u16* __restrict__ outB,
                                                  float* __restrict__ outF) {
    __shared__ __align__(16) u16 sa[2][128 * 32];  // 2 x 8 KB
    __shared__ __align__(16) u16 sb[2][128 * 32];  // 2 x 8 KB
    const int tid = threadIdx.x;
    const int tilesN = N >> 7;

    // XCD-aware bijective swizzle (grids here are divisible by 8)
    int bid = blockIdx.x;
    int nwg = gridDim.x;
    if ((nwg & 7) == 0) {
        int cpx = nwg >> 3;
        bid = (bid & 7) * cpx + (bid >> 3);
    }
    const int tm = bid / tilesN, tn = bid % tilesN;

    const int w = tid >> 6, l = tid & 63;
    const int wm = (w >> 2) * 64, wn = (w & 3) * 32;
    const int l15 = l & 15, l4 = l >> 4;

    // staging addresses (loop-invariant): thread loads 1 A chunk + 1 B chunk
    const int srow = tid >> 2, scol = tid & 3;
    const int scs = scol ^ ((srow >> 1) & 3);  // pre-swizzled global chunk
    int gm = tm * 128 + srow;
    gm = gm < Mreal ? gm : Mreal - 1;  // clamp (stores guarded)
    const u16* gA0 = A + (size_t)gm * K + scs * 8;
    const u16* gB0 = BT + (size_t)(tn * 128 + srow) * K + scs * 8;
    const int loff = tid * 8;  // linear in lane (gload_lds requirement)

    auto STAGE = [&](int buf, int kt) {
        const int k0 = kt << 5;
        gload16(gA0 + k0, &sa[buf][loff]);
        gload16(gB0 + k0, &sb[buf][loff]);
    };

    f32x4 acc[4][2];
    #pragma unroll
    for (int i = 0; i < 4; i++)
        #pragma unroll
        for (int j = 0; j < 2; j++) acc[i][j] = (f32x4){0.f, 0.f, 0.f, 0.f};

    const int nk = K >> 5;  // >= 14 for all shapes here
    STAGE(0, 0);
    STAGE(1, 1);

    #pragma unroll 1
    for (int kt = 0; kt < nk; ++kt) {
        const int cur = kt & 1;
        if (kt + 1 < nk) {
            asm volatile("s_waitcnt vmcnt(2)" ::: "memory");  // tile kt landed
        } else {
            asm volatile("s_waitcnt vmcnt(0)" ::: "memory");  // last tile
        }
        __builtin_amdgcn_s_barrier();
        __builtin_amdgcn_sched_barrier(0);
        {
            bf16x8 af[4], bfr[2];
            #pragma unroll
            for (int i = 0; i < 4; i++) {
                int row = wm + i * 16 + l15;
                int c = l4 ^ ((row >> 1) & 3);
                af[i] = *(const bf16x8*)&sa[cur][row * 32 + c * 8];
            }
            #pragma unroll
            for (int j = 0; j < 2; j++) {
                int row = wn + j * 16 + l15;
                int c = l4 ^ ((row >> 1) & 3);
                bfr[j] = *(const bf16x8*)&sb[cur][row * 32 + c * 8];
            }
            #pragma unroll
            for (int i = 0; i < 4; i++)
                #pragma unroll
                for (int j = 0; j < 2; j++)
                    acc[i][j] = MFMA(af[i], bfr[j], acc[i][j]);
        }
        __builtin_amdgcn_s_barrier();  // all waves done reading buf cur
        __builtin_amdgcn_sched_barrier(0);
        if (kt + 2 < nk) STAGE(cur, kt + 2);  // refill freed buf; stays in flight
    }

    #pragma unroll
    for (int i = 0; i < 4; i++) {
        int row0 = tm * 128 + wm + i * 16 + l4 * 4;
        #pragma unroll
        for (int j = 0; j < 2; j++) {
            int col = tn * 128 + wn + j * 16 + l15;
            if (col >= Nreal) continue;
            float bv = bias[col];
            #pragma unroll
            for (int r = 0; r < 4; r++) {
                int m = row0 + r;
                if (m >= Mreal) continue;
                float v = acc[i][j][r] + bv;
                if (EPI == 0) {
                    outB[(size_t)m * Nreal + col] = f2bf(v);
                } else if (EPI == 1) {
                    float gl = 0.5f * v * (1.f + erff(v * 0.70710678118654752f));
                    outB[(size_t)m * Nreal + col] = f2bf(gl);
                } else if (EPI == 2) {
                    outB[(size_t)m * DIM + col] =
                        f2bf(xresF[(size_t)m * DIM + col] + ls[col] * v);
                } else {
                    outF[(size_t)m * DIM + col] =
                        bf2f(xres16[(size_t)m * DIM + col]) + ls[col] * v;
                }
            }
        }
    }
}

// ---------------- attention: one block per (b_local,h), 4 waves
__global__ __launch_bounds__(256) void attn_kernel(const u16* __restrict__ qkv,
                                                   const float* __restrict__ btab,
                                                   u16* __restrict__ ctx) {
    __shared__ __align__(16) u16 sq[64 * 40];
    __shared__ __align__(16) u16 sk[64 * 40];
    __shared__ __align__(16) u16 sv[128 * 72];  // v transposed [d][s]
    __shared__ __align__(16) u16 sp[64 * 72];   // probs bf16
    const int tid = threadIdx.x;
    const int bh = blockIdx.x;
    const int b = bh >> 3, h = bh & 7;
    const int w = tid >> 6, l = tid & 63, l15 = l & 15, l4 = l >> 4;
    const f32x4 Z4 = {0.f, 0.f, 0.f, 0.f};
    const size_t rowbase = (size_t)(b * SEQ) * QKV_N + h * 192;

    for (int c = tid; c < SEQ * 4; c += 256) {
        int s = c >> 2, ch = c & 3;
        *(uint4*)&sq[s * 40 + ch * 8] = *(const uint4*)(qkv + rowbase + (size_t)s * QKV_N + ch * 8);
        *(uint4*)&sk[s * 40 + ch * 8] = *(const uint4*)(qkv + rowbase + (size_t)s * QKV_N + 32 + ch * 8);
    }
    for (int c = tid; c < 15 * 5; c += 256) {
        int s = SEQ + c / 5, ch = c % 5;
        *(uint4*)&sq[s * 40 + ch * 8] = (uint4){0, 0, 0, 0};
        *(uint4*)&sk[s * 40 + ch * 8] = (uint4){0, 0, 0, 0};
    }
    for (int c = tid; c < SEQ * 16; c += 256) {
        int s = c >> 4, ch = c & 15;
        uint4 vv = *(const uint4*)(qkv + rowbase + (size_t)s * QKV_N + 64 + ch * 8);
        const u16* pv = (const u16*)&vv;
        #pragma unroll
        for (int j = 0; j < 8; j++) sv[(ch * 8 + j) * 72 + s] = pv[j];
    }
    for (int c = tid; c < 128 * 15; c += 256) {
        int d = c / 15, s = SEQ + c % 15;
        sv[d * 72 + s] = 0;
    }
    __syncthreads();

    bf16x8 aq = *(const bf16x8*)&sq[(w * 16 + l15) * 40 + l4 * 8];
    f32x4 sc[4];
    #pragma unroll
    for (int j = 0; j < 4; j++) {
        bf16x8 bk = *(const bf16x8*)&sk[(j * 16 + l15) * 40 + l4 * 8];
        sc[j] = MFMA(aq, bk, Z4);
    }
    #pragma unroll
    for (int r = 0; r < 4; r++) {
        int row = w * 16 + l4 * 4 + r;
        float pv[4];
        #pragma unroll
        for (int j = 0; j < 4; j++) {
            int col = j * 16 + l15;
            float sval = -1e30f;
            if (row < SEQ && col < SEQ)
                sval = sc[j][r] * SCALE + btab[(h * SEQ + row) * SEQ + col];
            pv[j] = sval;
        }
        float m = fmaxf(fmaxf(pv[0], pv[1]), fmaxf(pv[2], pv[3]));
        #pragma unroll
        for (int mask = 1; mask < 16; mask <<= 1) m = fmaxf(m, __shfl_xor(m, mask, 16));
        float s = 0.f;
        #pragma unroll
        for (int j = 0; j < 4; j++) { pv[j] = expf(pv[j] - m); s += pv[j]; }
        #pragma unroll
        for (int mask = 1; mask < 16; mask <<= 1) s += __shfl_xor(s, mask, 16);
        float inv = 1.f / s;
        #pragma unroll
        for (int j = 0; j < 4; j++) sp[row * 72 + j * 16 + l15] = f2bf(pv[j] * inv);
    }
    __syncthreads();

    bf16x8 ap0 = *(const bf16x8*)&sp[(w * 16 + l15) * 72 + l4 * 8];
    bf16x8 ap1 = *(const bf16x8*)&sp[(w * 16 + l15) * 72 + 32 + l4 * 8];
    #pragma unroll
    for (int j = 0; j < 8; j++) {
        bf16x8 b0 = *(const bf16x8*)&sv[(j * 16 + l15) * 72 + l4 * 8];
        bf16x8 b1 = *(const bf16x8*)&sv[(j * 16 + l15) * 72 + 32 + l4 * 8];
        f32x4 a = MFMA(ap0, b0, Z4);
        a = MFMA(ap1, b1, a);
        #pragma unroll
        for (int r = 0; r < 4; r++) {
            int row = w * 16 + l4 * 4 + r;
            if (row < SEQ)
                ctx[((size_t)(b * SEQ) + row) * 1024 + h * DV + j * 16 + l15] = f2bf(a[r]);
        }
    }
}

extern "C" void kernel_launch(void* const* d_in, const int* in_sizes, int n_in,
                              void* d_out, int out_size, void* d_ws, size_t ws_size,
                              hipStream_t stream) {
    const float* x = (const float*)d_in[0];
    const float* qkv_w = (const float*)d_in[1];
    const float* qkv_b = (const float*)d_in[2];
    const float* proj_w = (const float*)d_in[3];
    const float* proj_b = (const float*)d_in[4];
    const float* ln1_g = (const float*)d_in[5];
    const float* ln1_b = (const float*)d_in[6];
    const float* ln2_g = (const float*)d_in[7];
    const float* ln2_b = (const float*)d_in[8];
    const float* mlp_w1 = (const float*)d_in[9];
    const float* mlp_b1 = (const float*)d_in[10];
    const float* mlp_w2 = (const float*)d_in[11];
    const float* mlp_b2 = (const float*)d_in[12];
    const float* attn_biases = (const float*)d_in[13];
    const float* ls1 = (const float*)d_in[14];
    const float* ls2 = (const float*)d_in[15];
    const int* bias_idxs = (const int*)d_in[16];
    int n_off = in_sizes[13] / NH;
    float* out = (float*)d_out;

    auto al = [](size_t b) { return (b + 255) & ~(size_t)255; };
    const size_t wbytes = al((size_t)QKV_N * DIM * 2) + al((size_t)512 * 1024 * 2) +
                          al((size_t)MLP_H * DIM * 2) + al((size_t)512 * MLP_H * 2) +
                          al((size_t)NH * 2401 * 4);

    // pick largest chunk (fewest chunks) that fits ws_size
    int nc = 32;
    {
        const int cands[6] = {1, 2, 4, 8, 16, 32};
        for (int ci = 0; ci < 6; ci++) {
            size_t R = (size_t)(BATCH / cands[ci]) * SEQ;
            size_t need = wbytes + al(R * DIM * 2) + al(R * MLP_H * 2) + al(R * 1024 * 2);
            if (need <= ws_size) { nc = cands[ci]; break; }
        }
    }
    const int CH = BATCH / nc;      // batches per chunk
    const int R = CH * SEQ;         // rows per chunk
    const int MT = (R + 127) >> 7;  // M tiles per chunk

    char* ws = (char*)d_ws;
    size_t off = 0;
    auto alloc = [&](size_t bytes) {
        void* p = ws + off;
        off += al(bytes);
        return p;
    };
    u16* wt_qkv = (u16*)alloc((size_t)QKV_N * DIM * 2);
    u16* wt_proj = (u16*)alloc((size_t)512 * 1024 * 2);
    u16* wt_m1 = (u16*)alloc((size_t)MLP_H * DIM * 2);
    u16* wt_m2 = (u16*)alloc((size_t)512 * MLP_H * 2);
    float* btab = (float*)alloc((size_t)NH * 2401 * 4);
    u16* hbuf = (u16*)alloc((size_t)R * DIM * 2);    // h(LN1) -> xmid16 (proj out)
    u16* big = (u16*)alloc((size_t)R * MLP_H * 2);   // qkv -> m1
    u16* ctx = (u16*)alloc((size_t)R * 1024 * 2);    // attn ctx -> h2(LN2 out)

    transpose_cast<<<(DIM / 32) * (QKV_N / 32), 256, 0, stream>>>(qkv_w, wt_qkv, DIM, QKV_N, QKV_N);
    transpose_cast<<<(1024 / 32) * (512 / 32), 256, 0, stream>>>(proj_w, wt_proj, 1024, DIM, 512);
    transpose_cast<<<(DIM / 32) * (MLP_H / 32), 256, 0, stream>>>(mlp_w1, wt_m1, DIM, MLP_H, MLP_H);
    transpose_cast<<<(MLP_H / 32) * (512 / 32), 256, 0, stream>>>(mlp_w2, wt_m2, MLP_H, DIM, 512);
    build_bias<<<(NH * 2401 + 255) / 256, 256, 0, stream>>>(attn_biases, bias_idxs, btab, n_off);

    for (int c = 0; c < nc; ++c) {
        const float* xc = x + (size_t)c * R * DIM;
        float* oc = out + (size_t)c * R * DIM;

        // LN1: x (f32) -> h (bf16, hbuf)
        ln_kernel<<<R / 4, 256, 0, stream>>>(xc, ln1_g, ln1_b, hbuf);
        // QKV: h @ Wqkv -> big
        gemm128<0><<<MT * (QKV_N / 128), 512, 0, stream>>>(
            hbuf, wt_qkv, R, QKV_N, DIM, QKV_N, qkv_b, nullptr, nullptr, nullptr, big, nullptr);
        // attention: big -> ctx
        attn_kernel<<<CH * NH, 256, 0, stream>>>(big, btab, ctx);
        // proj + residual1 -> xmid16 in hbuf (hbuf dead after QKV)
        gemm128<2><<<MT * 4, 512, 0, stream>>>(
            ctx, wt_proj, R, 512, 1024, DIM, proj_b, ls1, xc, nullptr, hbuf, nullptr);
        // LN2: xmid16 (hbuf) -> h2 (ctx; dead after proj)
        ln16_kernel<<<R / 4, 256, 0, stream>>>(hbuf, ln2_g, ln2_b, ctx);
        // MLP1 + gelu: h2 (ctx) -> big (qkv dead)
        gemm128<1><<<MT * (MLP_H / 128), 512, 0, stream>>>(
            ctx, wt_m1, R, MLP_H, DIM, MLP_H, mlp_b1, nullptr, nullptr, nullptr, big, nullptr);
        // MLP2 + residual2: big, xmid16 (hbuf) -> out (f32)
        gemm128<3><<<MT * 4, 512, 0, stream>>>(
            big, wt_m2, R, 512, MLP_H, DIM, mlp_b2, ls2, nullptr, hbuf, nullptr, oc);
    }
}